// Round 1
// 469.269 us; speedup vs baseline: 1.1127x; 1.1127x over previous
//
#include <hip/hip_runtime.h>
#include <hip/hip_bf16.h>

// ---------------------------------------------------------------------------
// ConvTokenEmbedder: char-CNN -> 2x highway -> projection
// R8 = R7 with gemm_hw rebuilt as a 256^2-tile 8-phase pipelined GEMM
//     (T3+T4 counted vmcnt + T5 setprio + T1 XCD swizzle), keeping the
//     proven XOR chunk-swizzle LDS layout (bank-conflict-free ds_read_b128).
//     Stage order per tile T: ph0 B1(T+1), ph1 A0(T+1), ph2 A1(T+1),
//     ph3 B0(T+2); single s_waitcnt vmcnt(2) per K-tile (never 0 mid-loop).
// Conv: 4 uniform template launches, W register-resident, X double-buffered.
// ---------------------------------------------------------------------------

#define NTOK 4096
#define NF   2048
#define KDIM 2048
#define HID  4096
#define PDIM 512

typedef __attribute__((ext_vector_type(4))) float floatx4;
typedef __attribute__((ext_vector_type(8))) short shortx8;

__device__ inline void async_copy16(const void* g, void* l) {
  __builtin_amdgcn_global_load_lds(
      (const __attribute__((address_space(1))) void*)(uintptr_t)g,
      (__attribute__((address_space(3))) void*)(uint32_t)(uintptr_t)l,
      16, 0, 0);
}

__device__ inline void block_barrier() {
  asm volatile("" ::: "memory");
  __builtin_amdgcn_s_barrier();
  asm volatile("" ::: "memory");
}

// ---------------------------------------------------------------------------
__global__ __launch_bounds__(256) void cvt_kernel(
    const float* __restrict__ s, __hip_bfloat16* __restrict__ d, int n) {
  int i = blockIdx.x * 256 + threadIdx.x;
  if (i < n) d[i] = __float2bfloat16(s[i]);
}

// Highway weight cvt with nl/gate row interleave: dst row r = src row
// (r>>1) + (r&1)*2048. So cols 2j/2j+1 of p' are (nl_j, gate_j).
__global__ __launch_bounds__(256) void cvt_hw(
    const float* __restrict__ s, __hip_bfloat16* __restrict__ d) {
  int i = blockIdx.x * 256 + threadIdx.x;  // over 4096*2048
  int r = i >> 11, k = i & 2047;
  int sr = (r >> 1) + (r & 1) * 2048;
  d[i] = __float2bfloat16(s[(size_t)sr * 2048 + k]);
}

// ---------------------------------------------------------------------------
// Conv weight prep: Wb[ch][kp], kp = k*16+d, K padded to 128 (zeros k>=w).
// Plus bias pack [2048] and bf16 emb table [262*16].
// ---------------------------------------------------------------------------
__global__ __launch_bounds__(256) void conv_wprep(
    const float* __restrict__ w0, const float* __restrict__ w1,
    const float* __restrict__ w2, const float* __restrict__ w3,
    const float* __restrict__ w4, const float* __restrict__ w5,
    const float* __restrict__ w6,
    const float* __restrict__ b0, const float* __restrict__ b1,
    const float* __restrict__ b2, const float* __restrict__ b3,
    const float* __restrict__ b4, const float* __restrict__ b5,
    const float* __restrict__ b6, const float* __restrict__ emb,
    __hip_bfloat16* __restrict__ Wb, float* __restrict__ Bc,
    __hip_bfloat16* __restrict__ embb) {
  int idx = blockIdx.x * 256 + threadIdx.x;
  const int start[7] = {0, 32, 64, 128, 256, 512, 1024};
  const float* ws[7] = {w0, w1, w2, w3, w4, w5, w6};
  const float* bs[7] = {b0, b1, b2, b3, b4, b5, b6};
  if (idx < 262144) {
    int ch = idx >> 7, kp = idx & 127;
    int f = (ch >= 32) + (ch >= 64) + (ch >= 128) + (ch >= 256) +
            (ch >= 512) + (ch >= 1024);
    int w = f + 1, lc = ch - start[f];
    int d = kp & 15, k = kp >> 4;
    float v = (k < w) ? ws[f][((size_t)lc * 16 + d) * w + k] : 0.f;
    Wb[idx] = __float2bfloat16(v);
  } else if (idx < 262144 + 2048) {
    int ch = idx - 262144;
    int f = (ch >= 32) + (ch >= 64) + (ch >= 128) + (ch >= 256) +
            (ch >= 512) + (ch >= 1024);
    Bc[ch] = bs[f][ch - start[f]];
  } else if (idx < 262144 + 2048 + 4192) {
    int e = idx - 262144 - 2048;
    embb[e] = __float2bfloat16(emb[e]);
  }
}

// ---------------------------------------------------------------------------
// Conv kernel (one template instantiation per width class -> uniform LDS).
// Block: 64 channels x 32 tokens; 8 groups of 4 tokens (one per wave).
// ---------------------------------------------------------------------------
template <int NKT, int NT, int ROWS>
__global__ __launch_bounds__(256) void conv_k(
    const int* __restrict__ chars, const __hip_bfloat16* __restrict__ embb,
    const __hip_bfloat16* __restrict__ Wb, const float* __restrict__ bias,
    __hip_bfloat16* __restrict__ h, int chbase) {
  __shared__ __align__(16) __hip_bfloat16 Xs[2 * 4 * ROWS * 24];
  int tid = threadIdx.x, wave = tid >> 6, lane = tid & 63;
  int frow = lane & 15, q = lane >> 4;
  int chb = chbase + blockIdx.y * 64;
  int tokbase = blockIdx.x * 32;

  shortx8 wreg[NKT][4];
#pragma unroll
  for (int kt = 0; kt < NKT; ++kt)
#pragma unroll
    for (int j = 0; j < 4; ++j)
      wreg[kt][j] = *(const shortx8*)(
          Wb + (size_t)(chb + j * 16 + frow) * 128 + kt * 32 + q * 8);

  float blane = bias[chb + lane];
  int Tvj[4];
#pragma unroll
  for (int j = 0; j < 4; ++j) {
    int ch = chb + j * 16 + frow;
    int w = 1 + (ch >= 32) + (ch >= 64) + (ch >= 128) + (ch >= 256) +
            (ch >= 512) + (ch >= 1024);
    Tvj[j] = 51 - w;
  }

  auto stage = [&](int g, int buf) {
    constexpr int NST = 4 * ROWS;
#pragma unroll
    for (int rep = 0; rep < (NST + 255) / 256; ++rep) {
      int rr = tid + rep * 256;
      if (rr < NST) {
        int tk = rr / ROWS, r = rr - tk * ROWS;
        __hip_bfloat16* dst = Xs + ((size_t)(buf * 4 + tk) * ROWS + r) * 24;
        if (r < 50) {
          int c = chars[(size_t)(tokbase + g * 4 + tk) * 50 + r];
          const shortx8* e = (const shortx8*)(embb + c * 16);
          *(shortx8*)(dst) = e[0];
          *(shortx8*)(dst + 8) = e[1];
        } else if (g <= 1) {
          shortx8 z = {0, 0, 0, 0, 0, 0, 0, 0};
          *(shortx8*)(dst) = z;
          *(shortx8*)(dst + 8) = z;
        }
      }
    }
  };

  stage(0, 0);
  __syncthreads();

  const floatx4 zero = {0.f, 0.f, 0.f, 0.f};
#pragma unroll 1
  for (int g = 0; g < 8; ++g) {
    if (g < 7) stage(g + 1, (g + 1) & 1);

    const __hip_bfloat16* Xw = Xs + (size_t)((g & 1) * 4 + wave) * ROWS * 24;
    floatx4 acc[NT][4];

#pragma unroll
    for (int kt = 0; kt < NKT; ++kt) {
      int kk = kt * 2 + (q >> 1);
      int d0 = (q & 1) * 8;
      shortx8 xf[NT];
#pragma unroll
      for (int i = 0; i < NT; ++i)
        xf[i] = *(const shortx8*)(Xw + (i * 16 + frow + kk) * 24 + d0);
#pragma unroll
      for (int i = 0; i < NT; ++i)
#pragma unroll
        for (int j = 0; j < 4; ++j) {
          if (kt == 0)
            acc[i][j] = __builtin_amdgcn_mfma_f32_16x16x32_bf16(
                xf[i], wreg[0][j], zero, 0, 0, 0);
          else
            acc[i][j] = __builtin_amdgcn_mfma_f32_16x16x32_bf16(
                xf[i], wreg[kt][j], acc[i][j], 0, 0, 0);
        }
    }

    float vj[4];
#pragma unroll
    for (int j = 0; j < 4; ++j) {
      float v = -1e30f;
#pragma unroll
      for (int i = 0; i < NT; ++i) {
#pragma unroll
        for (int r = 0; r < 4; ++r) {
          if (i < 2) {
            v = fmaxf(v, acc[i][j][r]);
          } else {
            int t = i * 16 + q * 4 + r;
            if (t < Tvj[j]) v = fmaxf(v, acc[i][j][r]);
          }
        }
      }
      v = fmaxf(v, __shfl_xor(v, 16));
      v = fmaxf(v, __shfl_xor(v, 32));
      vj[j] = v;
    }
    float r0 = (q & 2) ? vj[2] : vj[0];
    float r1 = (q & 2) ? vj[3] : vj[1];
    float rv = (q & 1) ? r1 : r0;
    int tok = tokbase + g * 4 + wave;
    h[(size_t)tok * NF + chb + lane] =
        __float2bfloat16(fmaxf(rv + blane, 0.f));
    __syncthreads();
  }
}

// ---------------------------------------------------------------------------
// Highway-fused GEMM, 256x256 tile, 8-phase pipelined schedule.
//   8 waves = 2(M) x 4(N); per-wave output 128 rows x 64 cols.
//   LDS: As/Bs = 2 dbuf x 256 rows x 64 cols bf16 (64 KiB each, 128 KiB).
//   Row stride 64 elems (128 B); 8 chunks of 16 B per row; slot c of row r
//   holds global chunk c^(r&7)  (source-side swizzle, applied at staging;
//   frag ds_read_b128 sweeps all 8 bank groups -> 2-way only = free).
//   Phase p of tile T: {ds_read A-frag rows 2p,2p+1 (+ all B at p=0);
//   stage 1 half-tile; s_barrier; setprio(1); 16 MFMA; setprio(0);
//   [p=3: s_waitcnt vmcnt(2)]; s_barrier}.
//   Stage order: ph0 B1(T+1), ph1 A0(T+1), ph2 A1(T+1), ph3 B0(T+2).
//   Every overwritten half-tile has >=1 full barrier after its last read;
//   vmcnt(2) at ph3 leaves exactly B0(T+2)'s 2 loads in flight.
// Epilogue: pairs even/odd cols via shfl_xor(1), g=sigmoid(gate+b),
// h' = g*h + (1-g)*relu(nl+b), writes Hdst.
// ---------------------------------------------------------------------------
__global__ __launch_bounds__(512, 2) void gemm_hw8(
    const __hip_bfloat16* __restrict__ A, const __hip_bfloat16* __restrict__ B,
    const float* __restrict__ hwb, __hip_bfloat16* __restrict__ Hdst) {
  __shared__ __align__(16) __hip_bfloat16 As[2 * 256 * 64];
  __shared__ __align__(16) __hip_bfloat16 Bs[2 * 256 * 64];
  int tid = threadIdx.x;
  int wave = tid >> 6, lane = tid & 63;
  int wr = wave >> 2, wc = wave & 3;     // 2 x 4 wave grid
  int sr8 = lane >> 3, sc8 = lane & 7;   // staging row-in-seg / chunk slot
  int frow = lane & 15, q = lane >> 4;

  // Bijective XCD swizzle (grid 256, 256 % 8 == 0): XCD x gets bn {2x,2x+1},
  // sharing 2 A-panels (2 MiB) in its private L2.
  int wg = blockIdx.x;
  int swz = (wg & 7) * 32 + (wg >> 3);
  int bm = swz & 15;   // w tile (N dim)
  int bn = swz >> 4;   // token tile (M dim)

  const __hip_bfloat16* Ab = A + (size_t)bn * 256 * KDIM;
  const __hip_bfloat16* Bb = B + (size_t)bm * 256 * KDIM;

  floatx4 acc[8][4];
  const floatx4 zero = {0.f, 0.f, 0.f, 0.f};
#pragma unroll
  for (int i = 0; i < 8; ++i)
#pragma unroll
    for (int j = 0; j < 4; ++j) acc[i][j] = zero;

  // Stage one 16 KiB half-tile: 2 x global_load_lds(16B) per thread.
  // Dest base is wave-uniform (HW spreads lanes base+lane*16); source is
  // per-lane with the chunk swizzle gc = sc8 ^ sr8 pre-applied.
  auto stage_half = [&](const __hip_bfloat16* gsrc, __hip_bfloat16* lbase,
                        int d, int hf, int kb) {
#pragma unroll
    for (int it = 0; it < 2; ++it) {
      int row = hf * 128 + (wave * 2 + it) * 8;  // segment start row (uniform)
      int r = row + sr8;
      int gc = sc8 ^ sr8;
      async_copy16(gsrc + (size_t)r * KDIM + kb + gc * 8,
                   (char*)lbase + ((size_t)d * 256 + row) * 128);
    }
  };

  shortx8 b_[4][2];
  shortx8 aA[2][2];

#define LDA(Asd, i0)                                                         \
  {                                                                          \
    _Pragma("unroll") for (int ii = 0; ii < 2; ++ii) {                       \
      _Pragma("unroll") for (int s = 0; s < 2; ++s) {                        \
        int r = wr * 128 + ((i0) + ii) * 16 + frow;                          \
        aA[ii][s] = *(const shortx8*)((Asd) + r * 64 +                       \
                                      (((s * 4 + q) ^ (frow & 7)) << 3));    \
      }                                                                      \
    }                                                                        \
  }

#define LDB(Bsd)                                                             \
  {                                                                          \
    _Pragma("unroll") for (int j = 0; j < 4; ++j) {                          \
      _Pragma("unroll") for (int s = 0; s < 2; ++s) {                        \
        int r = wc * 64 + j * 16 + frow;                                     \
        b_[j][s] = *(const shortx8*)((Bsd) + r * 64 +                        \
                                     (((s * 4 + q) ^ (frow & 7)) << 3));     \
      }                                                                      \
    }                                                                        \
  }

#define MMA2(i0)                                                             \
  {                                                                          \
    __builtin_amdgcn_s_setprio(1);                                           \
    _Pragma("unroll") for (int s = 0; s < 2; ++s) {                          \
      _Pragma("unroll") for (int ii = 0; ii < 2; ++ii) {                     \
        _Pragma("unroll") for (int j = 0; j < 4; ++j) {                      \
          acc[(i0) + ii][j] = __builtin_amdgcn_mfma_f32_16x16x32_bf16(       \
              aA[ii][s], b_[j][s], acc[(i0) + ii][j], 0, 0, 0);              \
        }                                                                    \
      }                                                                      \
    }                                                                        \
    __builtin_amdgcn_s_setprio(0);                                           \
  }

  // Prologue: tile 0 fully staged + B0(1) in flight.
  stage_half(Bb, Bs, 0, 0, 0);
  stage_half(Bb, Bs, 0, 1, 0);
  stage_half(Ab, As, 0, 0, 0);
  stage_half(Ab, As, 0, 1, 0);
  stage_half(Bb, Bs, 1, 0, 64);
  asm volatile("s_waitcnt vmcnt(2)" ::: "memory");  // tile 0 done, B0(1) flies
  block_barrier();

  const int NTILE = KDIM / 64;  // 32
#pragma unroll 2
  for (int T = 0; T < NTILE; ++T) {
    int d = T & 1, d1 = d ^ 1;
    const __hip_bfloat16* Asd = As + d * 16384;
    const __hip_bfloat16* Bsd = Bs + d * 16384;
    int kn = (T + 1) * 64;

    // ---- phase 0: frag rows 0-1, all B frags; stage B1(T+1)
    LDA(Asd, 0);
    LDB(Bsd);
    if (T + 1 < NTILE) stage_half(Bb, Bs, d1, 1, kn);
    block_barrier();
    MMA2(0);
    block_barrier();

    // ---- phase 1: frag rows 2-3; stage A0(T+1)
    LDA(Asd, 2);
    if (T + 1 < NTILE) stage_half(Ab, As, d1, 0, kn);
    block_barrier();
    MMA2(2);
    block_barrier();

    // ---- phase 2: frag rows 4-5; stage A1(T+1)
    LDA(Asd, 4);
    if (T + 1 < NTILE) stage_half(Ab, As, d1, 1, kn);
    block_barrier();
    MMA2(4);
    block_barrier();

    // ---- phase 3: frag rows 6-7; stage B0(T+2); counted vmcnt
    LDA(Asd, 6);
    if (T + 2 < NTILE) stage_half(Bb, Bs, d, 0, kn + 64);
    block_barrier();
    MMA2(6);
    if (T + 2 < NTILE) {
      asm volatile("s_waitcnt vmcnt(2)" ::: "memory");  // tile T+1 complete
    } else if (T + 1 < NTILE) {
      asm volatile("s_waitcnt vmcnt(0)" ::: "memory");  // tail: no prefetch
    }
    block_barrier();
  }
#undef LDA
#undef LDB
#undef MMA2

  // Epilogue: highway gate fuse (identical math to R7).
  int crow0 = bn * 256 + wr * 128 + q * 4;
  int ccol0 = bm * 256 + wc * 64 + frow;
#pragma unroll
  for (int i = 0; i < 8; ++i)
#pragma unroll
    for (int j = 0; j < 4; ++j) {
      int gcol = ccol0 + j * 16;
      float bb = (gcol & 1) ? hwb[2048 + (gcol >> 1)] : hwb[gcol >> 1];
#pragma unroll
      for (int r = 0; r < 4; ++r) {
        int row = crow0 + i * 16 + r;
        float v = acc[i][j][r] + bb;
        float partner = __shfl_xor(v, 1);
        if (!(lane & 1)) {  // even lane holds nl, partner is gate pre-act
          float gte = 1.f / (1.f + expf(-partner));
          int ch = gcol >> 1;
          float hold = __bfloat162float(A[(size_t)row * 2048 + ch]);
          float hnew = gte * hold + (1.f - gte) * fmaxf(v, 0.f);
          Hdst[(size_t)row * 2048 + ch] = __float2bfloat16(hnew);
        }
      }
    }
}

// ---------------------------------------------------------------------------
// Projection GEMM: 32x128 tile (grid 4x128 = 512 blocks, 2/CU), BK=64,
// same XOR swizzle. C fp32 + bias.
// ---------------------------------------------------------------------------
__global__ __launch_bounds__(256) void gemm_proj(
    const __hip_bfloat16* __restrict__ A, const __hip_bfloat16* __restrict__ B,
    float* __restrict__ C, const float* __restrict__ bias) {
  const int K = KDIM;
  __shared__ __align__(16) __hip_bfloat16 As[32 * 64];
  __shared__ __align__(16) __hip_bfloat16 Bs[128 * 64];
  int tid = threadIdx.x;
  int wave = tid >> 6, lane = tid & 63;
  int wr = wave >> 1, wc = wave & 1;
  int bn = blockIdx.y, bm = blockIdx.x;

  int sr8 = lane >> 3, sc8 = lane & 7;
  int frow = lane & 15, q = lane >> 4;

  floatx4 acc[4];
  floatx4 zero = {0.f, 0.f, 0.f, 0.f};
#pragma unroll
  for (int j = 0; j < 4; ++j) acc[j] = zero;

  const __hip_bfloat16* Ab = A + (size_t)bn * 32 * K;
  const __hip_bfloat16* Bb = B + (size_t)bm * 128 * K;

  for (int kb = 0; kb < K; kb += 64) {
    __syncthreads();
    {
      int r = wave * 8 + sr8;
      int gc = sc8 ^ (r & 7);
      async_copy16(Ab + (size_t)r * K + kb + gc * 8, (char*)As + wave * 1024);
    }
#pragma unroll
    for (int it = 0; it < 4; ++it) {
      int seg = wave * 4 + it;
      int r = seg * 8 + sr8;
      int gc = sc8 ^ (r & 7);
      async_copy16(Bb + (size_t)r * K + kb + gc * 8, (char*)Bs + seg * 1024);
    }
    __syncthreads();

#pragma unroll
    for (int s = 0; s < 2; ++s) {
      shortx8 af, bf[4];
      {
        int r = wr * 16 + frow;
        af = *(const shortx8*)(As + r * 64 + ((s * 4 + q) ^ (r & 7)) * 8);
      }
#pragma unroll
      for (int j = 0; j < 4; ++j) {
        int r = wc * 64 + j * 16 + frow;
        bf[j] = *(const shortx8*)(Bs + r * 64 + ((s * 4 + q) ^ (r & 7)) * 8);
      }
#pragma unroll
      for (int j = 0; j < 4; ++j)
        acc[j] = __builtin_amdgcn_mfma_f32_16x16x32_bf16(af, bf[j], acc[j],
                                                          0, 0, 0);
    }
  }

  int crow0 = bn * 32 + wr * 16 + q * 4;
  int ccol0 = bm * 128 + wc * 64 + frow;
#pragma unroll
  for (int j = 0; j < 4; ++j) {
    int c = ccol0 + j * 16;
#pragma unroll
    for (int r = 0; r < 4; ++r) {
      int row = crow0 + r;
      C[(size_t)row * PDIM + c] = acc[j][r] + bias[c];
    }
  }
}

// ---------------------------------------------------------------------------
extern "C" void kernel_launch(void* const* d_in, const int* in_sizes, int n_in,
                              void* d_out, int out_size, void* d_ws, size_t ws_size,
                              hipStream_t stream) {
  const int*   chars  = (const int*)d_in[1];
  const float* emb    = (const float*)d_in[2];
  const float* cw[7];
  const float* cb[7];
  for (int i = 0; i < 7; ++i) {
    cw[i] = (const float*)d_in[3 + 2 * i];
    cb[i] = (const float*)d_in[4 + 2 * i];
  }
  const float* hw_w0  = (const float*)d_in[17];
  const float* hw_b0  = (const float*)d_in[18];
  const float* hw_w1  = (const float*)d_in[19];
  const float* hw_b1  = (const float*)d_in[20];
  const float* proj_w = (const float*)d_in[21];
  const float* proj_b = (const float*)d_in[22];
  float* out = (float*)d_out;

  // Workspace (82 MiB):
  //   [0,16)   h   bf16 4096x2048      [16,32) h2  bf16 4096x2048
  //   [32,48)  convWb 512KB + convBc 8KB + embb 8.4KB
  //   [48,64)  w0b  [64,80) w1b  [80,82) pwb
  char* ws = (char*)d_ws;
  __hip_bfloat16* h      = (__hip_bfloat16*)(ws);
  __hip_bfloat16* h2     = (__hip_bfloat16*)(ws + (16ull << 20));
  __hip_bfloat16* convWb = (__hip_bfloat16*)(ws + (32ull << 20));
  float*          convBc = (float*)(ws + (32ull << 20) + 524288);
  __hip_bfloat16* embb   = (__hip_bfloat16*)(ws + (32ull << 20) + 524288 + 8192);
  __hip_bfloat16* w0b    = (__hip_bfloat16*)(ws + (48ull << 20));
  __hip_bfloat16* w1b    = (__hip_bfloat16*)(ws + (64ull << 20));
  __hip_bfloat16* pwb    = (__hip_bfloat16*)(ws + (80ull << 20));

  cvt_hw<<<(HID * KDIM) / 256, 256, 0, stream>>>(hw_w0, w0b);
  cvt_hw<<<(HID * KDIM) / 256, 256, 0, stream>>>(hw_w1, w1b);
  cvt_kernel<<<(PDIM * KDIM) / 256, 256, 0, stream>>>(proj_w, pwb, PDIM * KDIM);
  conv_wprep<<<(262144 + 2048 + 4192 + 255) / 256, 256, 0, stream>>>(
      cw[0], cw[1], cw[2], cw[3], cw[4], cw[5], cw[6],
      cb[0], cb[1], cb[2], cb[3], cb[4], cb[5], cb[6], emb,
      convWb, convBc, embb);

  // Conv: one launch per width class (uniform LDS/template per launch).
  conv_k<1, 4, 72><<<dim3(128, 1), 256, 0, stream>>>(chars, embb, convWb,
                                                     convBc, h, 0);
  conv_k<2, 3, 56><<<dim3(128, 3), 256, 0, stream>>>(chars, embb, convWb,
                                                     convBc, h, 64);
  conv_k<3, 3, 56><<<dim3(128, 12), 256, 0, stream>>>(chars, embb, convWb,
                                                      convBc, h, 256);
  conv_k<4, 3, 56><<<dim3(128, 16), 256, 0, stream>>>(chars, embb, convWb,
                                                      convBc, h, 1024);

  // 256^2-tile 8-phase highway GEMMs: grid 256 (1 block/CU), 512 threads.
  gemm_hw8<<<dim3(256), 512, 0, stream>>>(h, w0b, hw_b0, h2);
  gemm_hw8<<<dim3(256), 512, 0, stream>>>(h2, w1b, hw_b1, h);
  gemm_proj<<<dim3(PDIM / 128, NTOK / 32), 256, 0, stream>>>(h, pwb, out,
                                                             proj_b);
}

// Round 2
// 448.406 us; speedup vs baseline: 1.1645x; 1.0465x over previous
//
#include <hip/hip_runtime.h>
#include <hip/hip_bf16.h>

// ---------------------------------------------------------------------------
// ConvTokenEmbedder: char-CNN -> 2x highway -> projection
// R9 = R8 with gemm_hw8's K-tile restructured to 2 barriers/tile + deep
//     prefetch: all frag ds_reads issued intra-tile (no per-phase barriers),
//     s-major 8x8-MFMA sub-phases, A(T+1) staged at tile start (full-tile
//     latency cover), B(T+2) staged after the mid-tile barrier, single
//     counted s_waitcnt vmcnt(4) per tile. Register budget held at R8's
//     level (aU/aV+b0/b1 = 48 VGPR) to keep 2 waves/SIMD.
//     Also: fp32->bf16 cvt kernels vectorized (float4x2 -> shortx8).
// Conv: 4 uniform template launches, W register-resident, X double-buffered.
// ---------------------------------------------------------------------------

#define NTOK 4096
#define NF   2048
#define KDIM 2048
#define HID  4096
#define PDIM 512

typedef __attribute__((ext_vector_type(4))) float floatx4;
typedef __attribute__((ext_vector_type(8))) short shortx8;

__device__ inline void async_copy16(const void* g, void* l) {
  __builtin_amdgcn_global_load_lds(
      (const __attribute__((address_space(1))) void*)(uintptr_t)g,
      (__attribute__((address_space(3))) void*)(uint32_t)(uintptr_t)l,
      16, 0, 0);
}

__device__ inline void block_barrier() {
  asm volatile("" ::: "memory");
  __builtin_amdgcn_s_barrier();
  asm volatile("" ::: "memory");
}

// ---------------------------------------------------------------------------
// Vectorized fp32 -> bf16 (8 elems/thread).
__global__ __launch_bounds__(256) void cvt8_kernel(
    const float* __restrict__ s, __hip_bfloat16* __restrict__ d, int n8) {
  int i = blockIdx.x * 256 + threadIdx.x;
  if (i < n8) {
    floatx4 v0 = *(const floatx4*)(s + (size_t)i * 8);
    floatx4 v1 = *(const floatx4*)(s + (size_t)i * 8 + 4);
    union { shortx8 v; __hip_bfloat16 h[8]; } u;
#pragma unroll
    for (int t = 0; t < 4; ++t) u.h[t] = __float2bfloat16(v0[t]);
#pragma unroll
    for (int t = 0; t < 4; ++t) u.h[4 + t] = __float2bfloat16(v1[t]);
    *(shortx8*)(d + (size_t)i * 8) = u.v;
  }
}

// Highway weight cvt with nl/gate row interleave: dst row r = src row
// (r>>1) + (r&1)*2048. So cols 2j/2j+1 of p' are (nl_j, gate_j).
// Vectorized: 8 consecutive k per thread (row-uniform).
__global__ __launch_bounds__(256) void cvt_hw8(
    const float* __restrict__ s, __hip_bfloat16* __restrict__ d) {
  int i = blockIdx.x * 256 + threadIdx.x;  // over 4096*2048/8
  int r = i >> 8;             // 256 threads per 2048-wide row
  int kb = (i & 255) * 8;
  int sr = (r >> 1) + (r & 1) * 2048;
  const float* src = s + (size_t)sr * 2048 + kb;
  floatx4 v0 = *(const floatx4*)(src);
  floatx4 v1 = *(const floatx4*)(src + 4);
  union { shortx8 v; __hip_bfloat16 h[8]; } u;
#pragma unroll
  for (int t = 0; t < 4; ++t) u.h[t] = __float2bfloat16(v0[t]);
#pragma unroll
  for (int t = 0; t < 4; ++t) u.h[4 + t] = __float2bfloat16(v1[t]);
  *(shortx8*)(d + (size_t)r * 2048 + kb) = u.v;
}

// ---------------------------------------------------------------------------
// Conv weight prep: Wb[ch][kp], kp = k*16+d, K padded to 128 (zeros k>=w).
// Plus bias pack [2048] and bf16 emb table [262*16].
// ---------------------------------------------------------------------------
__global__ __launch_bounds__(256) void conv_wprep(
    const float* __restrict__ w0, const float* __restrict__ w1,
    const float* __restrict__ w2, const float* __restrict__ w3,
    const float* __restrict__ w4, const float* __restrict__ w5,
    const float* __restrict__ w6,
    const float* __restrict__ b0, const float* __restrict__ b1,
    const float* __restrict__ b2, const float* __restrict__ b3,
    const float* __restrict__ b4, const float* __restrict__ b5,
    const float* __restrict__ b6, const float* __restrict__ emb,
    __hip_bfloat16* __restrict__ Wb, float* __restrict__ Bc,
    __hip_bfloat16* __restrict__ embb) {
  int idx = blockIdx.x * 256 + threadIdx.x;
  const int start[7] = {0, 32, 64, 128, 256, 512, 1024};
  const float* ws[7] = {w0, w1, w2, w3, w4, w5, w6};
  const float* bs[7] = {b0, b1, b2, b3, b4, b5, b6};
  if (idx < 262144) {
    int ch = idx >> 7, kp = idx & 127;
    int f = (ch >= 32) + (ch >= 64) + (ch >= 128) + (ch >= 256) +
            (ch >= 512) + (ch >= 1024);
    int w = f + 1, lc = ch - start[f];
    int d = kp & 15, k = kp >> 4;
    float v = (k < w) ? ws[f][((size_t)lc * 16 + d) * w + k] : 0.f;
    Wb[idx] = __float2bfloat16(v);
  } else if (idx < 262144 + 2048) {
    int ch = idx - 262144;
    int f = (ch >= 32) + (ch >= 64) + (ch >= 128) + (ch >= 256) +
            (ch >= 512) + (ch >= 1024);
    Bc[ch] = bs[f][ch - start[f]];
  } else if (idx < 262144 + 2048 + 4192) {
    int e = idx - 262144 - 2048;
    embb[e] = __float2bfloat16(emb[e]);
  }
}

// ---------------------------------------------------------------------------
// Conv kernel (one template instantiation per width class -> uniform LDS).
// Block: 64 channels x 32 tokens; 8 groups of 4 tokens (one per wave).
// ---------------------------------------------------------------------------
template <int NKT, int NT, int ROWS>
__global__ __launch_bounds__(256) void conv_k(
    const int* __restrict__ chars, const __hip_bfloat16* __restrict__ embb,
    const __hip_bfloat16* __restrict__ Wb, const float* __restrict__ bias,
    __hip_bfloat16* __restrict__ h, int chbase) {
  __shared__ __align__(16) __hip_bfloat16 Xs[2 * 4 * ROWS * 24];
  int tid = threadIdx.x, wave = tid >> 6, lane = tid & 63;
  int frow = lane & 15, q = lane >> 4;
  int chb = chbase + blockIdx.y * 64;
  int tokbase = blockIdx.x * 32;

  shortx8 wreg[NKT][4];
#pragma unroll
  for (int kt = 0; kt < NKT; ++kt)
#pragma unroll
    for (int j = 0; j < 4; ++j)
      wreg[kt][j] = *(const shortx8*)(
          Wb + (size_t)(chb + j * 16 + frow) * 128 + kt * 32 + q * 8);

  float blane = bias[chb + lane];
  int Tvj[4];
#pragma unroll
  for (int j = 0; j < 4; ++j) {
    int ch = chb + j * 16 + frow;
    int w = 1 + (ch >= 32) + (ch >= 64) + (ch >= 128) + (ch >= 256) +
            (ch >= 512) + (ch >= 1024);
    Tvj[j] = 51 - w;
  }

  auto stage = [&](int g, int buf) {
    constexpr int NST = 4 * ROWS;
#pragma unroll
    for (int rep = 0; rep < (NST + 255) / 256; ++rep) {
      int rr = tid + rep * 256;
      if (rr < NST) {
        int tk = rr / ROWS, r = rr - tk * ROWS;
        __hip_bfloat16* dst = Xs + ((size_t)(buf * 4 + tk) * ROWS + r) * 24;
        if (r < 50) {
          int c = chars[(size_t)(tokbase + g * 4 + tk) * 50 + r];
          const shortx8* e = (const shortx8*)(embb + c * 16);
          *(shortx8*)(dst) = e[0];
          *(shortx8*)(dst + 8) = e[1];
        } else if (g <= 1) {
          shortx8 z = {0, 0, 0, 0, 0, 0, 0, 0};
          *(shortx8*)(dst) = z;
          *(shortx8*)(dst + 8) = z;
        }
      }
    }
  };

  stage(0, 0);
  __syncthreads();

  const floatx4 zero = {0.f, 0.f, 0.f, 0.f};
#pragma unroll 1
  for (int g = 0; g < 8; ++g) {
    if (g < 7) stage(g + 1, (g + 1) & 1);

    const __hip_bfloat16* Xw = Xs + (size_t)((g & 1) * 4 + wave) * ROWS * 24;
    floatx4 acc[NT][4];

#pragma unroll
    for (int kt = 0; kt < NKT; ++kt) {
      int kk = kt * 2 + (q >> 1);
      int d0 = (q & 1) * 8;
      shortx8 xf[NT];
#pragma unroll
      for (int i = 0; i < NT; ++i)
        xf[i] = *(const shortx8*)(Xw + (i * 16 + frow + kk) * 24 + d0);
#pragma unroll
      for (int i = 0; i < NT; ++i)
#pragma unroll
        for (int j = 0; j < 4; ++j) {
          if (kt == 0)
            acc[i][j] = __builtin_amdgcn_mfma_f32_16x16x32_bf16(
                xf[i], wreg[0][j], zero, 0, 0, 0);
          else
            acc[i][j] = __builtin_amdgcn_mfma_f32_16x16x32_bf16(
                xf[i], wreg[kt][j], acc[i][j], 0, 0, 0);
        }
    }

    float vj[4];
#pragma unroll
    for (int j = 0; j < 4; ++j) {
      float v = -1e30f;
#pragma unroll
      for (int i = 0; i < NT; ++i) {
#pragma unroll
        for (int r = 0; r < 4; ++r) {
          if (i < 2) {
            v = fmaxf(v, acc[i][j][r]);
          } else {
            int t = i * 16 + q * 4 + r;
            if (t < Tvj[j]) v = fmaxf(v, acc[i][j][r]);
          }
        }
      }
      v = fmaxf(v, __shfl_xor(v, 16));
      v = fmaxf(v, __shfl_xor(v, 32));
      vj[j] = v;
    }
    float r0 = (q & 2) ? vj[2] : vj[0];
    float r1 = (q & 2) ? vj[3] : vj[1];
    float rv = (q & 1) ? r1 : r0;
    int tok = tokbase + g * 4 + wave;
    h[(size_t)tok * NF + chb + lane] =
        __float2bfloat16(fmaxf(rv + blane, 0.f));
    __syncthreads();
  }
}

// ---------------------------------------------------------------------------
// Highway-fused GEMM, 256x256 tile, deep-pipelined, 2 barriers per K-tile.
//   8 waves = 2(M) x 4(N); per-wave output 128 rows x 64 cols.
//   LDS: As/Bs = 2 dbuf x 256 x 64 bf16 (64 KiB each). XOR chunk swizzle:
//   slot c of row r holds global chunk c^(r&7) (source-side at staging).
//   K-tile (s-major, 8 sub-phases x 8 MFMA):
//     t0: ldb4(b0,s0); lda2(aU,r01,s0); stage A(T+1) x2; lda2(aV,r23,s0); MMA8
//     t1: lda2(aU,r45,s0); MMA8    t2: lda2(aV,r67,s0); ldb4(b1,s1); MMA8
//     t3: lda2(aU,r01,s1); MMA8    t4: lda2(aV,r23,s1); MMA8; BARRIER
//     t5: stage B(T+2) hf0; lda2(aU,r45,s1); MMA8
//     t6: stage B(T+2) hf1; lda2(aV,r67,s1); MMA8
//     t7: MMA8; s_waitcnt vmcnt(4); BARRIER
//   Hazards: A(T+1)->d1-A issued after tile-boundary barrier (all A(T-1)
//   ds_reads complete before it, lgkm-enforced). B(T+2)->d-B issued after
//   mid-tile barrier (all waves' B(T) reads complete: b1 consumed at t4).
//   vmcnt(4) leaves exactly B(T+2)'s 4 loads in flight; in-order retirement
//   makes it cover A(T+1) (issued earlier) and everything older.
//   Cover: A(T+1) ~full tile; B(T+2) ~10 sub-phases.
// Epilogue: pairs even/odd cols via shfl_xor(1), g=sigmoid(gate+b),
// h' = g*h + (1-g)*relu(nl+b), writes Hdst.
// ---------------------------------------------------------------------------
__global__ __launch_bounds__(512, 2) void gemm_hw8(
    const __hip_bfloat16* __restrict__ A, const __hip_bfloat16* __restrict__ B,
    const float* __restrict__ hwb, __hip_bfloat16* __restrict__ Hdst) {
  __shared__ __align__(16) __hip_bfloat16 As[2 * 256 * 64];
  __shared__ __align__(16) __hip_bfloat16 Bs[2 * 256 * 64];
  int tid = threadIdx.x;
  int wave = tid >> 6, lane = tid & 63;
  int wr = wave >> 2, wc = wave & 3;     // 2 x 4 wave grid
  int sr8 = lane >> 3, sc8 = lane & 7;   // staging row-in-seg / chunk slot
  int frow = lane & 15, q = lane >> 4;

  // Bijective XCD swizzle (grid 256, 256 % 8 == 0): XCD x gets bn {2x,2x+1}.
  int wg = blockIdx.x;
  int swz = (wg & 7) * 32 + (wg >> 3);
  int bm = swz & 15;   // w tile (N dim)
  int bn = swz >> 4;   // token tile (M dim)

  const __hip_bfloat16* Ab = A + (size_t)bn * 256 * KDIM;
  const __hip_bfloat16* Bb = B + (size_t)bm * 256 * KDIM;

  floatx4 acc[8][4];
  const floatx4 zero = {0.f, 0.f, 0.f, 0.f};
#pragma unroll
  for (int i = 0; i < 8; ++i)
#pragma unroll
    for (int j = 0; j < 4; ++j) acc[i][j] = zero;

  // Stage one 16 KiB half-tile: 2 x global_load_lds(16B) per thread.
  auto stage_half = [&](const __hip_bfloat16* gsrc, __hip_bfloat16* lbase,
                        int d, int hf, int kb) {
#pragma unroll
    for (int it = 0; it < 2; ++it) {
      int row = hf * 128 + (wave * 2 + it) * 8;  // segment start row (uniform)
      int r = row + sr8;
      int gc = sc8 ^ sr8;
      async_copy16(gsrc + (size_t)r * KDIM + kb + gc * 8,
                   (char*)lbase + ((size_t)d * 256 + row) * 128);
    }
  };

  auto lda2 = [&](shortx8* dst2, const __hip_bfloat16* Asd, int i0, int s) {
#pragma unroll
    for (int ii = 0; ii < 2; ++ii) {
      int r = wr * 128 + (i0 + ii) * 16 + frow;
      dst2[ii] = *(const shortx8*)(Asd + r * 64 +
                                   (((s * 4 + q) ^ (frow & 7)) << 3));
    }
  };
  auto ldb4 = [&](shortx8* dst4, const __hip_bfloat16* Bsd, int s) {
#pragma unroll
    for (int j = 0; j < 4; ++j) {
      int r = wc * 64 + j * 16 + frow;
      dst4[j] = *(const shortx8*)(Bsd + r * 64 +
                                  (((s * 4 + q) ^ (frow & 7)) << 3));
    }
  };
  auto mma8 = [&](const shortx8* aX, const shortx8* bX, int i0) {
    __builtin_amdgcn_s_setprio(1);
#pragma unroll
    for (int ii = 0; ii < 2; ++ii)
#pragma unroll
      for (int j = 0; j < 4; ++j)
        acc[i0 + ii][j] = __builtin_amdgcn_mfma_f32_16x16x32_bf16(
            aX[ii], bX[j], acc[i0 + ii][j], 0, 0, 0);
    __builtin_amdgcn_s_setprio(0);
  };

  // Prologue: tile 0 fully staged + B(1) in flight.
  stage_half(Ab, As, 0, 0, 0);
  stage_half(Ab, As, 0, 1, 0);
  stage_half(Bb, Bs, 0, 0, 0);
  stage_half(Bb, Bs, 0, 1, 0);
  stage_half(Bb, Bs, 1, 0, 64);
  stage_half(Bb, Bs, 1, 1, 64);
  asm volatile("s_waitcnt vmcnt(4)" ::: "memory");  // tile 0 done, B(1) flies
  block_barrier();

  const int NTILE = KDIM / 64;  // 32
#pragma unroll 2
  for (int T = 0; T < NTILE; ++T) {
    int d = T & 1, d1 = d ^ 1;
    const __hip_bfloat16* Asd = As + d * 16384;
    const __hip_bfloat16* Bsd = Bs + d * 16384;
    int kn = (T + 1) * 64;

    shortx8 aU[2], aV[2], b0[4], b1[4];
    // t0
    ldb4(b0, Bsd, 0);
    lda2(aU, Asd, 0, 0);
    if (T + 1 < NTILE) {
      stage_half(Ab, As, d1, 0, kn);
      stage_half(Ab, As, d1, 1, kn);
    }
    lda2(aV, Asd, 2, 0);
    mma8(aU, b0, 0);
    // t1
    lda2(aU, Asd, 4, 0);
    mma8(aV, b0, 2);
    // t2
    lda2(aV, Asd, 6, 0);
    ldb4(b1, Bsd, 1);
    mma8(aU, b0, 4);
    // t3
    lda2(aU, Asd, 0, 1);
    mma8(aV, b0, 6);
    // t4
    lda2(aV, Asd, 2, 1);
    mma8(aU, b1, 0);
    block_barrier();  // all waves past all B(T) reads -> B(T+2) stage safe
    // t5
    if (T + 2 < NTILE) stage_half(Bb, Bs, d, 0, kn + 64);
    lda2(aU, Asd, 4, 1);
    mma8(aV, b1, 2);
    // t6
    if (T + 2 < NTILE) stage_half(Bb, Bs, d, 1, kn + 64);
    lda2(aV, Asd, 6, 1);
    mma8(aU, b1, 4);
    // t7
    mma8(aV, b1, 6);
    if (T + 2 < NTILE) {
      asm volatile("s_waitcnt vmcnt(4)" ::: "memory");  // tile T+1 complete
    } else if (T + 1 < NTILE) {
      asm volatile("s_waitcnt vmcnt(0)" ::: "memory");  // tail drain
    }
    block_barrier();
  }

  // Epilogue: highway gate fuse (identical math to R7/R8).
  int crow0 = bn * 256 + wr * 128 + q * 4;
  int ccol0 = bm * 256 + wc * 64 + frow;
#pragma unroll
  for (int i = 0; i < 8; ++i)
#pragma unroll
    for (int j = 0; j < 4; ++j) {
      int gcol = ccol0 + j * 16;
      float bb = (gcol & 1) ? hwb[2048 + (gcol >> 1)] : hwb[gcol >> 1];
#pragma unroll
      for (int r = 0; r < 4; ++r) {
        int row = crow0 + i * 16 + r;
        float v = acc[i][j][r] + bb;
        float partner = __shfl_xor(v, 1);
        if (!(lane & 1)) {  // even lane holds nl, partner is gate pre-act
          float gte = 1.f / (1.f + expf(-partner));
          int ch = gcol >> 1;
          float hold = __bfloat162float(A[(size_t)row * 2048 + ch]);
          float hnew = gte * hold + (1.f - gte) * fmaxf(v, 0.f);
          Hdst[(size_t)row * 2048 + ch] = __float2bfloat16(hnew);
        }
      }
    }
}

// ---------------------------------------------------------------------------
// Projection GEMM: 32x128 tile (grid 4x128 = 512 blocks, 2/CU), BK=64,
// same XOR swizzle. C fp32 + bias.
// ---------------------------------------------------------------------------
__global__ __launch_bounds__(256) void gemm_proj(
    const __hip_bfloat16* __restrict__ A, const __hip_bfloat16* __restrict__ B,
    float* __restrict__ C, const float* __restrict__ bias) {
  const int K = KDIM;
  __shared__ __align__(16) __hip_bfloat16 As[32 * 64];
  __shared__ __align__(16) __hip_bfloat16 Bs[128 * 64];
  int tid = threadIdx.x;
  int wave = tid >> 6, lane = tid & 63;
  int wr = wave >> 1, wc = wave & 1;
  int bn = blockIdx.y, bm = blockIdx.x;

  int sr8 = lane >> 3, sc8 = lane & 7;
  int frow = lane & 15, q = lane >> 4;

  floatx4 acc[4];
  floatx4 zero = {0.f, 0.f, 0.f, 0.f};
#pragma unroll
  for (int j = 0; j < 4; ++j) acc[j] = zero;

  const __hip_bfloat16* Ab = A + (size_t)bn * 32 * K;
  const __hip_bfloat16* Bb = B + (size_t)bm * 128 * K;

  for (int kb = 0; kb < K; kb += 64) {
    __syncthreads();
    {
      int r = wave * 8 + sr8;
      int gc = sc8 ^ (r & 7);
      async_copy16(Ab + (size_t)r * K + kb + gc * 8, (char*)As + wave * 1024);
    }
#pragma unroll
    for (int it = 0; it < 4; ++it) {
      int seg = wave * 4 + it;
      int r = seg * 8 + sr8;
      int gc = sc8 ^ (r & 7);
      async_copy16(Bb + (size_t)r * K + kb + gc * 8, (char*)Bs + seg * 1024);
    }
    __syncthreads();

#pragma unroll
    for (int s = 0; s < 2; ++s) {
      shortx8 af, bf[4];
      {
        int r = wr * 16 + frow;
        af = *(const shortx8*)(As + r * 64 + ((s * 4 + q) ^ (r & 7)) * 8);
      }
#pragma unroll
      for (int j = 0; j < 4; ++j) {
        int r = wc * 64 + j * 16 + frow;
        bf[j] = *(const shortx8*)(Bs + r * 64 + ((s * 4 + q) ^ (r & 7)) * 8);
      }
#pragma unroll
      for (int j = 0; j < 4; ++j)
        acc[j] = __builtin_amdgcn_mfma_f32_16x16x32_bf16(af, bf[j], acc[j],
                                                          0, 0, 0);
    }
  }

  int crow0 = bn * 32 + wr * 16 + q * 4;
  int ccol0 = bm * 128 + wc * 64 + frow;
#pragma unroll
  for (int j = 0; j < 4; ++j) {
    int c = ccol0 + j * 16;
#pragma unroll
    for (int r = 0; r < 4; ++r) {
      int row = crow0 + r;
      C[(size_t)row * PDIM + c] = acc[j][r] + bias[c];
    }
  }
}

// ---------------------------------------------------------------------------
extern "C" void kernel_launch(void* const* d_in, const int* in_sizes, int n_in,
                              void* d_out, int out_size, void* d_ws, size_t ws_size,
                              hipStream_t stream) {
  const int*   chars  = (const int*)d_in[1];
  const float* emb    = (const float*)d_in[2];
  const float* cw[7];
  const float* cb[7];
  for (int i = 0; i < 7; ++i) {
    cw[i] = (const float*)d_in[3 + 2 * i];
    cb[i] = (const float*)d_in[4 + 2 * i];
  }
  const float* hw_w0  = (const float*)d_in[17];
  const float* hw_b0  = (const float*)d_in[18];
  const float* hw_w1  = (const float*)d_in[19];
  const float* hw_b1  = (const float*)d_in[20];
  const float* proj_w = (const float*)d_in[21];
  const float* proj_b = (const float*)d_in[22];
  float* out = (float*)d_out;

  // Workspace (82 MiB):
  //   [0,16)   h   bf16 4096x2048      [16,32) h2  bf16 4096x2048
  //   [32,48)  convWb 512KB + convBc 8KB + embb 8.4KB
  //   [48,64)  w0b  [64,80) w1b  [80,82) pwb
  char* ws = (char*)d_ws;
  __hip_bfloat16* h      = (__hip_bfloat16*)(ws);
  __hip_bfloat16* h2     = (__hip_bfloat16*)(ws + (16ull << 20));
  __hip_bfloat16* convWb = (__hip_bfloat16*)(ws + (32ull << 20));
  float*          convBc = (float*)(ws + (32ull << 20) + 524288);
  __hip_bfloat16* embb   = (__hip_bfloat16*)(ws + (32ull << 20) + 524288 + 8192);
  __hip_bfloat16* w0b    = (__hip_bfloat16*)(ws + (48ull << 20));
  __hip_bfloat16* w1b    = (__hip_bfloat16*)(ws + (64ull << 20));
  __hip_bfloat16* pwb    = (__hip_bfloat16*)(ws + (80ull << 20));

  cvt_hw8<<<(HID * KDIM / 8) / 256, 256, 0, stream>>>(hw_w0, w0b);
  cvt_hw8<<<(HID * KDIM / 8) / 256, 256, 0, stream>>>(hw_w1, w1b);
  cvt8_kernel<<<(PDIM * KDIM / 8) / 256, 256, 0, stream>>>(proj_w, pwb,
                                                           PDIM * KDIM / 8);
  conv_wprep<<<(262144 + 2048 + 4192 + 255) / 256, 256, 0, stream>>>(
      cw[0], cw[1], cw[2], cw[3], cw[4], cw[5], cw[6],
      cb[0], cb[1], cb[2], cb[3], cb[4], cb[5], cb[6], emb,
      convWb, convBc, embb);

  // Conv: one launch per width class (uniform LDS/template per launch).
  conv_k<1, 4, 72><<<dim3(128, 1), 256, 0, stream>>>(chars, embb, convWb,
                                                     convBc, h, 0);
  conv_k<2, 3, 56><<<dim3(128, 3), 256, 0, stream>>>(chars, embb, convWb,
                                                     convBc, h, 64);
  conv_k<3, 3, 56><<<dim3(128, 12), 256, 0, stream>>>(chars, embb, convWb,
                                                      convBc, h, 256);
  conv_k<4, 3, 56><<<dim3(128, 16), 256, 0, stream>>>(chars, embb, convWb,
                                                      convBc, h, 1024);

  // 256^2-tile deep-pipelined highway GEMMs: grid 256 (1 block/CU), 512 thr.
  gemm_hw8<<<dim3(256), 512, 0, stream>>>(h, w0b, hw_b0, h2);
  gemm_hw8<<<dim3(256), 512, 0, stream>>>(h2, w1b, hw_b1, h);
  gemm_proj<<<dim3(PDIM / 128, NTOK / 32), 256, 0, stream>>>(h, pwb, out,
                                                             proj_b);
}